// Round 1
// baseline (901.501 us; speedup 1.0000x reference)
//
#include <hip/hip_runtime.h>

#define S_LEN 2048
#define BATCH 2
#define HID 4096
#define NH 32
#define NKV 8
#define DH 128
#define MROWS (BATCH*S_LEN)   // 4096

typedef unsigned short u16;
typedef unsigned int u32;
typedef __bf16 bf16x8 __attribute__((ext_vector_type(8)));
typedef float f32x4 __attribute__((ext_vector_type(4)));
typedef u16 u16x8 __attribute__((ext_vector_type(8)));

__device__ __forceinline__ u16 f2bf(float f) {
  union { float f; u32 u; } v; v.f = f;
  u32 r = (v.u + 0x7FFFu + ((v.u >> 16) & 1u)) >> 16;
  return (u16)r;
}
__device__ __forceinline__ float bf2f(u16 h) {
  union { u32 u; float f; } v; v.u = ((u32)h) << 16;
  return v.f;
}
__device__ __forceinline__ void async16(const void* g, void* l) {
  __builtin_amdgcn_global_load_lds(
      (const __attribute__((address_space(1))) u32*)g,
      (__attribute__((address_space(3))) u32*)l, 16, 0, 0);
}

// ---------------- fp32 -> bf16 conversion ----------------
__global__ __launch_bounds__(256) void cvt_f32_bf16(const float* __restrict__ in,
                                                    u16* __restrict__ out, int n) {
  int i0 = (blockIdx.x * 256 + threadIdx.x) * 8;
  if (i0 >= n) return;
  float4 a = *(const float4*)(in + i0);
  float4 b = *(const float4*)(in + i0 + 4);
  u16x8 r;
  r[0]=f2bf(a.x); r[1]=f2bf(a.y); r[2]=f2bf(a.z); r[3]=f2bf(a.w);
  r[4]=f2bf(b.x); r[5]=f2bf(b.y); r[6]=f2bf(b.z); r[7]=f2bf(b.w);
  *(u16x8*)(out + i0) = r;
}

// ---------------- NT bf16 GEMM: C[M,N] = A[M,K] * B[N,K]^T ----------------
// 128x128 tile, BK=32, 4 waves (2x2), each wave 4x4 fragments of 16x16x32.
// Double-buffered LDS; stage(next) issued after barrier so it overlaps MFMA.
template<int OUT_BF16>
__global__ __launch_bounds__(256) void gemm_nt(
    const u16* __restrict__ A, const u16* __restrict__ B, void* __restrict__ Cout,
    int M, int N, int K) {
  __shared__ u16 Al[2][128*32];
  __shared__ u16 Bl[2][128*32];
  int nTN = N >> 7;
  int nwg = gridDim.x;
  int id = ((int)blockIdx.x & 7) * (nwg >> 3) + ((int)blockIdx.x >> 3); // XCD swizzle (grid%8==0)
  int tm = id / nTN, tn = id % nTN;
  int m0 = tm << 7, n0 = tn << 7;
  int t = threadIdx.x;
  int w = t >> 6, lane = t & 63, lo = lane & 15, hi = lane >> 4;
  int wr = w >> 1, wc = w & 1;
  int rowA = (w << 4) + (lane >> 2);   // staging row within a 64-row group
  int ccA = lane & 3;                  // 16B chunk within 64B row

  const f32x4 fz = {0.f, 0.f, 0.f, 0.f};
  f32x4 acc[4][4];
#pragma unroll
  for (int i = 0; i < 4; ++i)
#pragma unroll
    for (int j = 0; j < 4; ++j) acc[i][j] = fz;

  int NK = K >> 5;
  auto stage = [&](int buf, int kt) {
    int k0 = kt << 5;
#pragma unroll
    for (int r = 0; r < 2; ++r) {
      const u16* g = A + (size_t)(m0 + (r << 6) + rowA) * K + k0 + ccA * 8;
      async16(g, (char*)&Al[buf][0] + (r << 12) + (w << 10));
    }
#pragma unroll
    for (int r = 0; r < 2; ++r) {
      const u16* g = B + (size_t)(n0 + (r << 6) + rowA) * K + k0 + ccA * 8;
      async16(g, (char*)&Bl[buf][0] + (r << 12) + (w << 10));
    }
  };

  stage(0, 0);
  int cur = 0;
  for (int kt = 0; kt < NK; ++kt) {
    __syncthreads();                       // drains stage(cur); prev reads done
    if (kt + 1 < NK) stage(cur ^ 1, kt + 1);  // overlaps with MFMA below
    bf16x8 af[4], bfv[4];
#pragma unroll
    for (int i = 0; i < 4; ++i)
      af[i] = *(const bf16x8*)(&Al[cur][((wr << 6) + (i << 4) + lo) * 32 + hi * 8]);
#pragma unroll
    for (int j = 0; j < 4; ++j)
      bfv[j] = *(const bf16x8*)(&Bl[cur][((wc << 6) + (j << 4) + lo) * 32 + hi * 8]);
#pragma unroll
    for (int i = 0; i < 4; ++i)
#pragma unroll
      for (int j = 0; j < 4; ++j)
        acc[i][j] = __builtin_amdgcn_mfma_f32_16x16x32_bf16(af[i], bfv[j], acc[i][j], 0, 0, 0);
    cur ^= 1;
  }

#pragma unroll
  for (int i = 0; i < 4; ++i)
#pragma unroll
    for (int j = 0; j < 4; ++j)
#pragma unroll
      for (int r = 0; r < 4; ++r) {
        int row = m0 + (wr << 6) + (i << 4) + (hi << 2) + r;
        int col = n0 + (wc << 6) + (j << 4) + lo;
        if (OUT_BF16) ((u16*)Cout)[(size_t)row * N + col] = f2bf(acc[i][j][r]);
        else          ((float*)Cout)[(size_t)row * N + col] = acc[i][j][r];
      }
}

// ---------------- RoPE (in-place on bf16, 4 pairs per thread) ----------------
__global__ __launch_bounds__(256) void rope_kernel(u16* __restrict__ X,
                                                   const int* __restrict__ pos,
                                                   int ncols) {
  int idx = blockIdx.x * 256 + threadIdx.x;
  int groups = ncols >> 3;          // groups of 4 (d,d+64) pairs per row
  int m = idx / groups;
  int gi = idx - m * groups;
  if (m >= MROWS) return;
  int head = gi >> 4;
  int d0 = (gi & 15) << 2;
  float p = (float)pos[m];
  u16* base = X + (size_t)m * ncols + head * 128;
  u16 xa[4], xb[4], oa[4], ob[4];
  *(uint2*)xa = *(const uint2*)(base + d0);
  *(uint2*)xb = *(const uint2*)(base + d0 + 64);
#pragma unroll
  for (int i = 0; i < 4; ++i) {
    float j = (float)(d0 + i);
    float inv = __expf(j * -0.14391156516030342f);  // ln(10000)/64
    float fr = p * inv;
    float s, c;
    sincosf(fr, &s, &c);
    float x1 = bf2f(xa[i]), x2 = bf2f(xb[i]);
    oa[i] = f2bf(x1 * c - x2 * s);
    ob[i] = f2bf(x2 * c + x1 * s);
  }
  *(uint2*)(base + d0) = *(uint2*)oa;
  *(uint2*)(base + d0 + 64) = *(uint2*)ob;
}

// ---------------- V transpose: Vb[m][g*128+d] -> Vt[(b*8+g)*128 + d][s] ----------------
__global__ __launch_bounds__(256) void transpose_v(const u16* __restrict__ V,
                                                   u16* __restrict__ Vt) {
  int bid = blockIdx.x;            // (b*8+g)*32 + stile
  int s0 = (bid & 31) << 6;
  int bg = bid >> 5;
  int b = bg >> 3, g = bg & 7;
  __shared__ u16 tile[64][128];
  int t = threadIdx.x;
#pragma unroll
  for (int r = 0; r < 4; ++r) {
    int c = (r << 8) + t;          // 16B chunks of the 64x128 tile
    int row = c >> 4, cc = c & 15;
    *(uint4*)&tile[row][cc * 8] =
        *(const uint4*)(V + (size_t)(b * S_LEN + s0 + row) * 1024 + g * 128 + cc * 8);
  }
  __syncthreads();
#pragma unroll
  for (int r = 0; r < 4; ++r) {
    int c = (r << 8) + t;
    int d = c >> 3, cs = c & 7;
    u16 tmp[8];
#pragma unroll
    for (int i = 0; i < 8; ++i) tmp[i] = tile[cs * 8 + i][d];
    *(uint4*)(Vt + ((size_t)bg * 128 + d) * S_LEN + s0 + cs * 8) = *(uint4*)tmp;
  }
}

// ---------------- Flash attention (causal, GQA 4:1) ----------------
// block = (b, h, 64-row q-tile); 4 waves x 16 q-rows; KV tile = 64.
// K staged [64][128], V^T staged [128][64]; both XOR-swizzled (chunk ^= row&7)
// via pre-swizzled global source so global_load_lds stays linear.
__global__ __launch_bounds__(256) void attn_kernel(
    const u16* __restrict__ Q, const u16* __restrict__ K,
    const u16* __restrict__ Vt, u16* __restrict__ O) {
  int bid = blockIdx.x;
  int qt = bid & 31;
  int h = (bid >> 5) & 31;
  int b = bid >> 10;
  int g = h >> 2;
  __shared__ u16 Kl[64 * 128];
  __shared__ u16 Vl[128 * 64];
  __shared__ u16 Pl[4][16 * 64];
  int t = threadIdx.x, w = t >> 6, lane = t & 63, lo = lane & 15, hi = lane >> 4;

  bf16x8 qf[4];
  {
    const u16* qb = Q + (size_t)(b * S_LEN + (qt << 6) + (w << 4) + lo) * 4096 + h * 128;
#pragma unroll
    for (int kk = 0; kk < 4; ++kk) qf[kk] = *(const bf16x8*)(qb + kk * 32 + hi * 8);
  }
  const f32x4 fz = {0.f, 0.f, 0.f, 0.f};
  f32x4 acc[8];
#pragma unroll
  for (int j = 0; j < 8; ++j) acc[j] = fz;
  float mrun[4] = {-1e30f, -1e30f, -1e30f, -1e30f};
  float lrun[4] = {0.f, 0.f, 0.f, 0.f};

  const u16* Kbase = K + (size_t)(b * S_LEN) * 1024 + g * 128;
  const u16* Vbase = Vt + (size_t)((b << 3) + g) * 128 * S_LEN;

  int ntiles = qt + 1;
  for (int tile = 0; tile < ntiles; ++tile) {
    int s0 = tile << 6;
#pragma unroll
    for (int r = 0; r < 4; ++r) {              // stage K tile
      int c = (r << 8) + (w << 6) + lane;
      int row = c >> 4, cc = c & 15;
      int src = cc ^ (row & 7);
      async16(Kbase + (size_t)(s0 + row) * 1024 + src * 8,
              (char*)Kl + (r << 12) + (w << 10));
    }
#pragma unroll
    for (int r = 0; r < 4; ++r) {              // stage V^T tile
      int c = (r << 8) + (w << 6) + lane;
      int row = c >> 3, cc = c & 7;
      int src = cc ^ (row & 7);
      async16(Vbase + (size_t)row * S_LEN + s0 + src * 8,
              (char*)Vl + (r << 12) + (w << 10));
    }
    __syncthreads();

    // QK^T: S[q(16) x k(64)] per wave
    f32x4 sf[4];
#pragma unroll
    for (int j = 0; j < 4; ++j) {
      f32x4 sv = fz;
#pragma unroll
      for (int kk = 0; kk < 4; ++kk) {
        int row = (j << 4) + lo;
        int ch = ((kk << 2) + hi) ^ (row & 7);
        bf16x8 kf = *(const bf16x8*)(Kl + row * 128 + ch * 8);
        sv = __builtin_amdgcn_mfma_f32_16x16x32_bf16(qf[kk], kf, sv, 0, 0, 0);
      }
      sf[j] = sv;
    }
    const float scale = 0.08838834764831845f;
#pragma unroll
    for (int j = 0; j < 4; ++j)
#pragma unroll
      for (int r = 0; r < 4; ++r) sf[j][r] *= scale;
    if (tile == qt) {                           // diagonal tile: causal mask
#pragma unroll
      for (int j = 0; j < 4; ++j)
#pragma unroll
        for (int r = 0; r < 4; ++r) {
          int qq = (w << 4) + (hi << 2) + r;
          if (((j << 4) + lo) > qq) sf[j][r] = -1e9f;
        }
    }
    float pmax[4];
#pragma unroll
    for (int r = 0; r < 4; ++r)
      pmax[r] = fmaxf(fmaxf(sf[0][r], sf[1][r]), fmaxf(sf[2][r], sf[3][r]));
#pragma unroll
    for (int mm = 1; mm <= 8; mm <<= 1)
#pragma unroll
      for (int r = 0; r < 4; ++r)
        pmax[r] = fmaxf(pmax[r], __shfl_xor(pmax[r], mm, 64));
    float fsc[4];
#pragma unroll
    for (int r = 0; r < 4; ++r) {
      float mn = fmaxf(mrun[r], pmax[r]);
      fsc[r] = __expf(mrun[r] - mn);
      mrun[r] = mn;
    }
    float psum[4] = {0.f, 0.f, 0.f, 0.f};
#pragma unroll
    for (int j = 0; j < 4; ++j)
#pragma unroll
      for (int r = 0; r < 4; ++r) {
        float pv = __expf(sf[j][r] - mrun[r]);
        sf[j][r] = pv;
        psum[r] += pv;
      }
#pragma unroll
    for (int mm = 1; mm <= 8; mm <<= 1)
#pragma unroll
      for (int r = 0; r < 4; ++r) psum[r] += __shfl_xor(psum[r], mm, 64);
#pragma unroll
    for (int r = 0; r < 4; ++r) lrun[r] = lrun[r] * fsc[r] + psum[r];
#pragma unroll
    for (int j = 0; j < 8; ++j)
#pragma unroll
      for (int r = 0; r < 4; ++r) acc[j][r] *= fsc[r];

    // P (16x64 bf16) -> per-wave LDS, swizzled, then PV
#pragma unroll
    for (int j = 0; j < 4; ++j)
#pragma unroll
      for (int r = 0; r < 4; ++r) {
        int q_ = (hi << 2) + r;
        int col = (j << 4) + lo;
        int ch = (col >> 3) ^ (q_ & 7);
        Pl[w][q_ * 64 + ch * 8 + (col & 7)] = f2bf(sf[j][r]);
      }
#pragma unroll
    for (int kk = 0; kk < 2; ++kk) {
      int pch = ((kk << 2) + hi) ^ (lo & 7);
      bf16x8 pf = *(const bf16x8*)(&Pl[w][lo * 64 + pch * 8]);
#pragma unroll
      for (int j2 = 0; j2 < 8; ++j2) {
        int vrow = (j2 << 4) + lo;
        int vch = ((kk << 2) + hi) ^ (vrow & 7);
        bf16x8 vf = *(const bf16x8*)(Vl + vrow * 64 + vch * 8);
        acc[j2] = __builtin_amdgcn_mfma_f32_16x16x32_bf16(pf, vf, acc[j2], 0, 0, 0);
      }
    }
    __syncthreads();
  }

  u16* ob = O + (size_t)(b * S_LEN + (qt << 6) + (w << 4)) * 4096 + h * 128;
#pragma unroll
  for (int j2 = 0; j2 < 8; ++j2)
#pragma unroll
    for (int r = 0; r < 4; ++r) {
      int q_ = (hi << 2) + r;
      ob[(size_t)q_ * 4096 + (j2 << 4) + lo] = f2bf(acc[j2][r] / lrun[r]);
    }
}

// ---------------- launch ----------------
extern "C" void kernel_launch(void* const* d_in, const int* in_sizes, int n_in,
                              void* d_out, int out_size, void* d_ws, size_t ws_size,
                              hipStream_t stream) {
  const float* hidden = (const float*)d_in[0];
  const int* pos = (const int*)d_in[1];
  const float* Wq = (const float*)d_in[2];
  const float* Wk = (const float*)d_in[3];
  const float* Wv = (const float*)d_in[4];
  const float* Wo = (const float*)d_in[5];
  float* out = (float*)d_out;

  u16* hb  = (u16*)d_ws;            // bf16 workspace layout (200 MiB total)
  u16* wqb = hb  + 16777216;
  u16* wkb = wqb + 16777216;
  u16* wvb = wkb + 4194304;
  u16* wob = wvb + 4194304;
  u16* Qb  = wob + 16777216;
  u16* Kb  = Qb  + 16777216;
  u16* Vb  = Kb  + 4194304;
  u16* Vtb = Vb  + 4194304;
  u16* Ob  = Vtb + 4194304;

  cvt_f32_bf16<<<8192, 256, 0, stream>>>(hidden, hb, 16777216);
  cvt_f32_bf16<<<8192, 256, 0, stream>>>(Wq, wqb, 16777216);
  cvt_f32_bf16<<<2048, 256, 0, stream>>>(Wk, wkb, 4194304);
  cvt_f32_bf16<<<2048, 256, 0, stream>>>(Wv, wvb, 4194304);
  cvt_f32_bf16<<<8192, 256, 0, stream>>>(Wo, wob, 16777216);

  gemm_nt<1><<<1024, 256, 0, stream>>>(hb, wqb, Qb, 4096, 4096, 4096);
  gemm_nt<1><<<256,  256, 0, stream>>>(hb, wkb, Kb, 4096, 1024, 4096);
  gemm_nt<1><<<256,  256, 0, stream>>>(hb, wvb, Vb, 4096, 1024, 4096);

  rope_kernel<<<8192, 256, 0, stream>>>(Qb, pos, 4096);
  rope_kernel<<<2048, 256, 0, stream>>>(Kb, pos, 1024);

  transpose_v<<<512, 256, 0, stream>>>(Vb, Vtb);

  attn_kernel<<<2048, 256, 0, stream>>>(Qb, Kb, Vtb, Ob);

  gemm_nt<0><<<1024, 256, 0, stream>>>(Ob, wob, out, 4096, 4096, 4096);
}

// Round 3
// 613.929 us; speedup vs baseline: 1.4684x; 1.4684x over previous
//
#include <hip/hip_runtime.h>

#define S_LEN 2048
#define BATCH 2
#define HID 4096
#define NH 32
#define NKV 8
#define DH 128
#define MROWS (BATCH*S_LEN)   // 4096
#define QKV_N 6144

typedef unsigned short u16;
typedef unsigned int u32;
typedef __bf16 bf16x8 __attribute__((ext_vector_type(8)));
typedef float f32x4 __attribute__((ext_vector_type(4)));
typedef u16 u16x8 __attribute__((ext_vector_type(8)));

__device__ __forceinline__ u16 f2bf(float f) {           // round-half-up (2 insts)
  union { float f; u32 u; } v; v.f = f;
  return (u16)((v.u + 0x8000u) >> 16);
}
__device__ __forceinline__ float bf2f(u16 h) {
  union { u32 u; float f; } v; v.u = ((u32)h) << 16;
  return v.f;
}
__device__ __forceinline__ u32 cvtpk(float a, float b) { // packs bf16(a)|bf16(b)<<16
  u32 r;
  asm("v_cvt_pk_bf16_f32 %0, %1, %2" : "=v"(r) : "v"(a), "v"(b));
  return r;
}
__device__ __forceinline__ void async16(const void* g, void* l) {
  __builtin_amdgcn_global_load_lds(
      (const __attribute__((address_space(1))) u32*)g,
      (__attribute__((address_space(3))) u32*)l, 16, 0, 0);
}

// ---------------- fp32 -> bf16 conversion ----------------
__global__ __launch_bounds__(256) void cvt_f32_bf16(const float* __restrict__ in,
                                                    u16* __restrict__ out, int n) {
  int i0 = (blockIdx.x * 256 + threadIdx.x) * 8;
  if (i0 >= n) return;
  float4 a = *(const float4*)(in + i0);
  float4 b = *(const float4*)(in + i0 + 4);
  u16x8 r;
  r[0]=f2bf(a.x); r[1]=f2bf(a.y); r[2]=f2bf(a.z); r[3]=f2bf(a.w);
  r[4]=f2bf(b.x); r[5]=f2bf(b.y); r[6]=f2bf(b.z); r[7]=f2bf(b.w);
  *(u16x8*)(out + i0) = r;
}

// ---------------- NT bf16 GEMM: C[M,N] = A[M,K] * B[N,K]^T ----------------
template<int OUT_BF16>
__global__ __launch_bounds__(256) void gemm_nt(
    const u16* __restrict__ A, const u16* __restrict__ B, void* __restrict__ Cout,
    int M, int N, int K) {
  __shared__ u16 Al[2][128*32];
  __shared__ u16 Bl[2][128*32];
  int nTN = N >> 7;
  int nwg = gridDim.x;
  int id = ((int)blockIdx.x & 7) * (nwg >> 3) + ((int)blockIdx.x >> 3); // XCD swizzle (grid%8==0)
  int tm = id / nTN, tn = id % nTN;
  int m0 = tm << 7, n0 = tn << 7;
  int t = threadIdx.x;
  int w = t >> 6, lane = t & 63, lo = lane & 15, hi = lane >> 4;
  int wr = w >> 1, wc = w & 1;
  int rowA = (w << 4) + (lane >> 2);
  int ccA = lane & 3;

  const f32x4 fz = {0.f, 0.f, 0.f, 0.f};
  f32x4 acc[4][4];
#pragma unroll
  for (int i = 0; i < 4; ++i)
#pragma unroll
    for (int j = 0; j < 4; ++j) acc[i][j] = fz;

  int NK = K >> 5;
  auto stage = [&](int buf, int kt) {
    int k0 = kt << 5;
#pragma unroll
    for (int r = 0; r < 2; ++r) {
      const u16* g = A + (size_t)(m0 + (r << 6) + rowA) * K + k0 + ccA * 8;
      async16(g, (char*)&Al[buf][0] + (r << 12) + (w << 10));
    }
#pragma unroll
    for (int r = 0; r < 2; ++r) {
      const u16* g = B + (size_t)(n0 + (r << 6) + rowA) * K + k0 + ccA * 8;
      async16(g, (char*)&Bl[buf][0] + (r << 12) + (w << 10));
    }
  };

  stage(0, 0);
  int cur = 0;
  for (int kt = 0; kt < NK; ++kt) {
    __syncthreads();
    if (kt + 1 < NK) stage(cur ^ 1, kt + 1);
    bf16x8 af[4], bfv[4];
#pragma unroll
    for (int i = 0; i < 4; ++i)
      af[i] = *(const bf16x8*)(&Al[cur][((wr << 6) + (i << 4) + lo) * 32 + hi * 8]);
#pragma unroll
    for (int j = 0; j < 4; ++j)
      bfv[j] = *(const bf16x8*)(&Bl[cur][((wc << 6) + (j << 4) + lo) * 32 + hi * 8]);
#pragma unroll
    for (int i = 0; i < 4; ++i)
#pragma unroll
      for (int j = 0; j < 4; ++j)
        acc[i][j] = __builtin_amdgcn_mfma_f32_16x16x32_bf16(af[i], bfv[j], acc[i][j], 0, 0, 0);
    cur ^= 1;
  }

#pragma unroll
  for (int i = 0; i < 4; ++i)
#pragma unroll
    for (int j = 0; j < 4; ++j)
#pragma unroll
      for (int r = 0; r < 4; ++r) {
        int row = m0 + (wr << 6) + (i << 4) + (hi << 2) + r;
        int col = n0 + (wc << 6) + (j << 4) + lo;
        if (OUT_BF16) ((u16*)Cout)[(size_t)row * N + col] = f2bf(acc[i][j][r]);
        else          ((float*)Cout)[(size_t)row * N + col] = acc[i][j][r];
      }
}

// ---------------- RoPE (in-place on bf16, optional output scale) ----------------
__global__ __launch_bounds__(256) void rope_kernel(u16* __restrict__ X,
                                                   const int* __restrict__ pos,
                                                   int ncols, int pitch, float scale) {
  int idx = blockIdx.x * 256 + threadIdx.x;
  int groups = ncols >> 3;
  int m = idx / groups;
  int gi = idx - m * groups;
  if (m >= MROWS) return;
  int head = gi >> 4;
  int d0 = (gi & 15) << 2;
  float p = (float)pos[m];
  u16* base = X + (size_t)m * pitch + head * 128;
  u16 xa[4], xb[4], oa[4], ob[4];
  *(uint2*)xa = *(const uint2*)(base + d0);
  *(uint2*)xb = *(const uint2*)(base + d0 + 64);
#pragma unroll
  for (int i = 0; i < 4; ++i) {
    float j = (float)(d0 + i);
    float inv = __expf(j * -0.14391156516030342f);  // ln(10000)/64
    float fr = p * inv;
    float s, c;
    sincosf(fr, &s, &c);
    float x1 = bf2f(xa[i]), x2 = bf2f(xb[i]);
    oa[i] = f2bf((x1 * c - x2 * s) * scale);
    ob[i] = f2bf((x2 * c + x1 * s) * scale);
  }
  *(uint2*)(base + d0) = *(uint2*)oa;
  *(uint2*)(base + d0 + 64) = *(uint2*)ob;
}

// ---------------- V transpose: QKV[m][5120 + g*128 + d] -> Vt[(b*8+g)*128 + d][s] ----------------
__global__ __launch_bounds__(256) void transpose_v(const u16* __restrict__ V,
                                                   u16* __restrict__ Vt) {
  int bid = blockIdx.x;
  int s0 = (bid & 31) << 6;
  int bg = bid >> 5;
  int b = bg >> 3, g = bg & 7;
  __shared__ u16 tile[64][128];
  int t = threadIdx.x;
#pragma unroll
  for (int r = 0; r < 4; ++r) {
    int c = (r << 8) + t;
    int row = c >> 4, cc = c & 15;
    *(uint4*)&tile[row][cc * 8] =
        *(const uint4*)(V + (size_t)(b * S_LEN + s0 + row) * QKV_N + g * 128 + cc * 8);
  }
  __syncthreads();
#pragma unroll
  for (int r = 0; r < 4; ++r) {
    int c = (r << 8) + t;
    int d = c >> 3, cs = c & 7;
    u16 tmp[8];
#pragma unroll
    for (int i = 0; i < 8; ++i) tmp[i] = tile[cs * 8 + i][d];
    *(uint4*)(Vt + ((size_t)bg * 128 + d) * S_LEN + s0 + cs * 8) = *(uint4*)tmp;
  }
}

// ---------------- Flash attention (causal, GQA 4:1), swapped-operand layout ----------------
// block = (b, h, 64-row q-tile, heavy-first); 4 waves x 16 q-rows; KV tile = 64.
// QK^T: mfma(K, Q) -> S^T (q = lane&15, softmax state lane-local).
// PV:   mfma(V^T, P^T) -> O^T (q = lane&15). P packed via v_cvt_pk_bf16_f32.
__global__ __launch_bounds__(256) void attn_kernel(
    const u16* __restrict__ Q, const u16* __restrict__ K,
    const u16* __restrict__ Vt, u16* __restrict__ O) {
  int bid = blockIdx.x;
  int qt = 31 - (bid >> 6);          // heavy tiles first
  int bh = bid & 63;
  int b = bh >> 5, h = bh & 31;
  int g = h >> 2;
  __shared__ u16 Kl[64 * 128];
  __shared__ u16 Vl[128 * 64];
  __shared__ u16 Pl[4][16 * 72];     // per-wave P^T / O-bounce, pitch 72 (16B-aligned rows)
  int t = threadIdx.x, w = t >> 6, lane = t & 63, lo = lane & 15, hi = lane >> 4;

  bf16x8 qf[4];   // B-operand: lane -> Q row (q=lo), c-octet 32*kk+8*hi
  {
    const u16* qb = Q + (size_t)(b * S_LEN + (qt << 6) + (w << 4) + lo) * QKV_N + h * 128;
#pragma unroll
    for (int kk = 0; kk < 4; ++kk) qf[kk] = *(const bf16x8*)(qb + kk * 32 + hi * 8);
  }
  const f32x4 fz = {0.f, 0.f, 0.f, 0.f};
  f32x4 acc[8];
#pragma unroll
  for (int f = 0; f < 8; ++f) acc[f] = fz;
  float mrun = -1e30f, lrun = 0.f;

  const u16* Kbase = K + (size_t)(b * S_LEN) * QKV_N + g * 128;
  const u16* Vbase = Vt + (size_t)((b << 3) + g) * 128 * S_LEN;

  int ntiles = qt + 1;
  for (int tile = 0; tile < ntiles; ++tile) {
    int s0 = tile << 6;
#pragma unroll
    for (int r = 0; r < 4; ++r) {              // stage K tile [64][128], chunk-swizzled
      int c = (r << 8) + (w << 6) + lane;
      int row = c >> 4, cc = c & 15;
      int src = cc ^ (row & 7);
      async16(Kbase + (size_t)(s0 + row) * QKV_N + src * 8,
              (char*)Kl + (r << 12) + (w << 10));
    }
#pragma unroll
    for (int r = 0; r < 4; ++r) {              // stage V^T tile [128][64], chunk-swizzled
      int c = (r << 8) + (w << 6) + lane;
      int row = c >> 3, cc = c & 7;
      int src = cc ^ (row & 7);
      async16(Vbase + (size_t)row * S_LEN + s0 + src * 8,
              (char*)Vl + (r << 12) + (w << 10));
    }
    __syncthreads();

    // S^T[k][q]: frag j rows k_rel = 16j+4hi+r, col q = lo
    f32x4 sf[4];
#pragma unroll
    for (int j = 0; j < 4; ++j) {
      f32x4 sv = fz;
#pragma unroll
      for (int kk = 0; kk < 4; ++kk) {
        int row = (j << 4) + lo;
        int ch = ((kk << 2) + hi) ^ (row & 7);
        bf16x8 kf = *(const bf16x8*)(Kl + row * 128 + ch * 8);
        sv = __builtin_amdgcn_mfma_f32_16x16x32_bf16(kf, qf[kk], sv, 0, 0, 0);
      }
      sf[j] = sv;
    }
    if (tile == qt) {                           // causal mask on diagonal tile
      int q_rel = (w << 4) + lo;
#pragma unroll
      for (int j = 0; j < 4; ++j)
#pragma unroll
        for (int r = 0; r < 4; ++r)
          if (((j << 4) + (hi << 2) + r) > q_rel) sf[j][r] = -1e9f;
    }
    // row max: in-lane 16 + cross-hi shuffle
    float pmax = sf[0][0];
#pragma unroll
    for (int j = 0; j < 4; ++j)
#pragma unroll
      for (int r = 0; r < 4; ++r) pmax = fmaxf(pmax, sf[j][r]);
    pmax = fmaxf(pmax, __shfl_xor(pmax, 16, 64));
    pmax = fmaxf(pmax, __shfl_xor(pmax, 32, 64));
    // defer-max rescale (THR=8)
    if (__any(pmax > mrun + 8.f)) {
      float mn = fmaxf(mrun, pmax);
      float fsc = __expf(mrun - mn);
      mrun = mn;
      lrun *= fsc;
#pragma unroll
      for (int f = 0; f < 8; ++f)
#pragma unroll
        for (int r = 0; r < 4; ++r) acc[f][r] *= fsc;
    }
    float psum = 0.f;
#pragma unroll
    for (int j = 0; j < 4; ++j)
#pragma unroll
      for (int r = 0; r < 4; ++r) {
        float p = __expf(sf[j][r] - mrun);
        sf[j][r] = p;
        psum += p;
      }
    psum += __shfl_xor(psum, 16, 64);
    psum += __shfl_xor(psum, 32, 64);
    lrun += psum;

    // P^T -> per-wave LDS [16 q][72 k], packed b64 writes (k = 16j+4hi+{0..3})
#pragma unroll
    for (int j = 0; j < 4; ++j) {
      uint2 pk;
      pk.x = cvtpk(sf[j][0], sf[j][1]);
      pk.y = cvtpk(sf[j][2], sf[j][3]);
      *(uint2*)&Pl[w][lo * 72 + (j << 4) + (hi << 2)] = pk;
    }
    // PV: acc[f] (+)= V^T(A) x P^T(B); O^T rows d=16f+4hi+r, col q=lo
#pragma unroll
    for (int kk = 0; kk < 2; ++kk) {
      bf16x8 pf = *(const bf16x8*)&Pl[w][lo * 72 + (kk << 5) + (hi << 3)];
#pragma unroll
      for (int f = 0; f < 8; ++f) {
        int vrow = (f << 4) + lo;
        int phys = ((kk << 2) + hi) ^ (vrow & 7);
        bf16x8 vf = *(const bf16x8*)(Vl + vrow * 64 + phys * 8);
        acc[f] = __builtin_amdgcn_mfma_f32_16x16x32_bf16(vf, pf, acc[f], 0, 0, 0);
      }
    }
    __syncthreads();
  }

  // epilogue: divide, bounce O^T -> O through per-wave LDS, coalesced stores
  float rl = 1.0f / lrun;
#pragma unroll
  for (int half = 0; half < 2; ++half) {
#pragma unroll
    for (int f2 = 0; f2 < 4; ++f2) {
      int f = (half << 2) + f2;
      uint2 pk;
      pk.x = cvtpk(acc[f][0] * rl, acc[f][1] * rl);
      pk.y = cvtpk(acc[f][2] * rl, acc[f][3] * rl);
      *(uint2*)&Pl[w][lo * 72 + (f2 << 4) + (hi << 2)] = pk;
    }
#pragma unroll
    for (int it = 0; it < 2; ++it) {
      int rowq = (lane >> 3) + (it << 3);
      int c8 = lane & 7;
      uint4 val = *(const uint4*)&Pl[w][rowq * 72 + c8 * 8];
      *(uint4*)(O + (size_t)(b * S_LEN + (qt << 6) + (w << 4) + rowq) * 4096 +
                h * 128 + (half << 6) + c8 * 8) = val;
    }
  }
}

// ---------------- launch ----------------
extern "C" void kernel_launch(void* const* d_in, const int* in_sizes, int n_in,
                              void* d_out, int out_size, void* d_ws, size_t ws_size,
                              hipStream_t stream) {
  const float* hidden = (const float*)d_in[0];
  const int* pos = (const int*)d_in[1];
  const float* Wq = (const float*)d_in[2];
  const float* Wk = (const float*)d_in[3];
  const float* Wv = (const float*)d_in[4];
  const float* Wo = (const float*)d_in[5];
  float* out = (float*)d_out;

  u16* hb   = (u16*)d_ws;                 // [4096][4096]
  u16* wqb  = hb   + 16777216;            // [4096][4096]  } contiguous -> fused
  u16* wkb  = wqb  + 16777216;            // [1024][4096]  }   B matrix [6144][4096]
  u16* wvb  = wkb  + 4194304;             // [1024][4096]  }
  u16* wob  = wvb  + 4194304;             // [4096][4096]
  u16* QKVb = wob  + 16777216;            // [4096][6144]
  u16* Vtb  = QKVb + 25165824;            // [16*128][2048]
  u16* Ob   = Vtb  + 4194304;             // [4096][4096]

  cvt_f32_bf16<<<8192, 256, 0, stream>>>(hidden, hb, 16777216);
  cvt_f32_bf16<<<8192, 256, 0, stream>>>(Wq, wqb, 16777216);
  cvt_f32_bf16<<<2048, 256, 0, stream>>>(Wk, wkb, 4194304);
  cvt_f32_bf16<<<2048, 256, 0, stream>>>(Wv, wvb, 4194304);
  cvt_f32_bf16<<<8192, 256, 0, stream>>>(Wo, wob, 16777216);

  gemm_nt<1><<<1536, 256, 0, stream>>>(hb, wqb, QKVb, 4096, QKV_N, 4096);  // fused QKV

  rope_kernel<<<8192, 256, 0, stream>>>(QKVb, pos, 4096, QKV_N, 0.08838834764831845f); // Q (pre-scaled)
  rope_kernel<<<2048, 256, 0, stream>>>(QKVb + 4096, pos, 1024, QKV_N, 1.0f);          // K

  transpose_v<<<512, 256, 0, stream>>>(QKVb + 5120, Vtb);

  attn_kernel<<<2048, 256, 0, stream>>>(QKVb, QKVb + 4096, Vtb, Ob);

  gemm_nt<0><<<1024, 256, 0, stream>>>(Ob, wob, out, 4096, 4096, 4096);
}